// Round 13
// baseline (206.494 us; speedup 1.0000x reference)
//
#include <hip/hip_runtime.h>
#include <hip/hip_bf16.h>

typedef __attribute__((ext_vector_type(8))) short s16x8;
typedef __attribute__((ext_vector_type(4))) float f32x4;
typedef unsigned short u16;

#define NTOK 49
#define CDIM 128
#define NWIN 4096
#define LOG2E 1.4426950408889634f
#define SCL (0.17677669529663687f * LOG2E)  // 32^-0.5 * log2(e), folded into q weights+bias

// LDS plan (u16 units), 16384 u16 = 32.0 KB, unchanged from r10/r12.
//  staging: xt [64][136] at 0 (aliases head regions 0/1/part-2; barrier-protected)
//  region (wave*4096): q [64][32] swz at 0, k [64][32] swz at 2048
//    after S^T reads: P [64][64] bytes XOR-swz; after PV: ao chunk [64][32] swz
// NEW (r13): 2 windows per block, grid 2048. Window B's global loads are issued
// mid-window-A (post P-write) and consumed after A's proj drains -> staging stall
// hidden. Zeros rows 49-63 rewritten per window (A's scatter clobbers them).
// launch_bounds (256,4): cap 128 VGPR. (256,5)->spill (r7); (256,8)->120 (r6).
// r11 lesson: do NOT hoist weight fragments across phases (remat/spill, -5us).
#define XT_STRIDE 136
#define HEAD_SZ 4096
#define K_OFF 2048
#define LDS_ELEMS 16384

__device__ __forceinline__ u16 f2bf(float f) {
    __hip_bfloat16 h = __float2bfloat16(f);
    return __builtin_bit_cast(u16, h);
}
__device__ __forceinline__ unsigned pk2(float a, float b) {
    return (unsigned)f2bf(a) | ((unsigned)f2bf(b) << 16);
}

// pkq: [(kt*24+ot)*64+lane]*8+r = qkv_w[o=ot*16+lr][c=kt*32+8g+r]; q rows (o<128) pre-scaled by SCL
// pkp: same layout, 8 o-tiles   = proj_w[o][c]
// bMv: [h][mt][nt][g][lr][r] = bias[q=16nt+lr][j=16mt+4g+r]*LOG2E; -1e30 where q or j >= 49
// bias2: [384] = qkv_b, q part (o<128) pre-scaled by SCL
__global__ void prep_kernel(const float* __restrict__ qkv_w,
                            const float* __restrict__ proj_w,
                            const float* __restrict__ rpb,
                            const int* __restrict__ rpi,
                            const float* __restrict__ qkv_b,
                            u16* __restrict__ pkq, u16* __restrict__ pkp,
                            float* __restrict__ bMv, float* __restrict__ bias2) {
    int idx = blockIdx.x * blockDim.x + threadIdx.x;
    if (idx < 49152) {
        int r = idx & 7, lane = (idx >> 3) & 63, tile = idx >> 9;
        int ot = tile % 24, kt = tile / 24;
        int o = ot * 16 + (lane & 15);
        int k = kt * 32 + ((lane >> 4) << 3) + r;
        float w = qkv_w[o * CDIM + k];
        if (o < 128) w *= SCL;
        pkq[idx] = f2bf(w);
    } else if (idx < 65536) {
        int i2 = idx - 49152;
        int r = i2 & 7, lane = (i2 >> 3) & 63, tile = i2 >> 9;
        int ot = tile & 7, kt = tile >> 3;
        int o = ot * 16 + (lane & 15);
        int k = kt * 32 + ((lane >> 4) << 3) + r;
        pkp[i2] = f2bf(proj_w[o * CDIM + k]);
    } else if (idx < 81920) {
        int i = idx - 65536;
        int r = i & 3, lr = (i >> 2) & 15, g = (i >> 6) & 3;
        int nt = (i >> 8) & 3, mt = (i >> 10) & 3, h = i >> 12;
        int q = nt * 16 + lr, j = mt * 16 + 4 * g + r;
        bMv[i] = (q < NTOK && j < NTOK) ? rpb[rpi[q * NTOK + j] * 4 + h] * LOG2E : -1e30f;
    } else if (idx < 82304) {
        int o = idx - 81920;
        bias2[o] = qkv_b[o] * (o < 128 ? SCL : 1.0f);
    }
}

// convert staged registers -> xt LDS tile (+ zero rows 49..63)
__device__ __forceinline__ void xt_write(u16* __restrict__ xt, const float4* xin, int tid) {
#pragma unroll
    for (int u = 0; u < 6; ++u) {
        int lin = (tid + u * 256) * 4;
        int i = lin >> 7, c = lin & 127;
        uint2 pkv;
        pkv.x = pk2(xin[u].x, xin[u].y);
        pkv.y = pk2(xin[u].z, xin[u].w);
        *reinterpret_cast<uint2*>(&xt[i * XT_STRIDE + c]) = pkv;
    }
    if (tid < 32) {
        int lin = (1536 + tid) * 4;
        int i = lin >> 7, c = lin & 127;
        uint2 pkv;
        pkv.x = pk2(xin[6].x, xin[6].y);
        pkv.y = pk2(xin[6].z, xin[6].w);
        *reinterpret_cast<uint2*>(&xt[i * XT_STRIDE + c]) = pkv;
    }
    const uint2 z2 = {0u, 0u};
#pragma unroll
    for (int u = 0; u < 2; ++u)
        *reinterpret_cast<uint2*>(&xt[NTOK * XT_STRIDE + (tid + u * 256) * 4]) = z2;
}

// one window: phases 2-5 (xt already staged + barrier'd). If issueNext, the next
// window's global loads are issued right after the P-write (consumed by caller).
__device__ __forceinline__ void win_body(
    u16* __restrict__ smem, float* __restrict__ outp,
    const float* __restrict__ bias2, const float* __restrict__ proj_b,
    const s16x8* __restrict__ pkqv, const s16x8* __restrict__ pkpv,
    const f32x4* __restrict__ bv4,
    const float* __restrict__ xpN, float4* xinN, bool issueNext,
    int wave, int lane, int g, int lr, int qs, int tid) {
    u16* xt = smem;

    // ---------- phase 2a: V-GEMM (x as A, weights as B); bias via C-init ----------
    f32x4 acc_v[4][2];
#pragma unroll
    for (int t1 = 0; t1 < 2; ++t1) {
        float vb = bias2[256 + (2 * wave + t1) * 16 + lr];
#pragma unroll
        for (int mt = 0; mt < 4; ++mt) acc_v[mt][t1] = (f32x4){vb, vb, vb, vb};
    }
#pragma unroll
    for (int kt = 0; kt < 4; ++kt) {
        s16x8 af[4];
#pragma unroll
        for (int tt = 0; tt < 4; ++tt)
            af[tt] = *reinterpret_cast<const s16x8*>(&xt[(tt * 16 + lr) * XT_STRIDE + kt * 32 + g * 8]);
        s16x8 wv[2];
#pragma unroll
        for (int t1 = 0; t1 < 2; ++t1)
            wv[t1] = pkqv[(kt * 24 + 16 + 2 * wave + t1) * 64 + lane];
        __builtin_amdgcn_s_setprio(1);
#pragma unroll
        for (int mt = 0; mt < 4; ++mt)
#pragma unroll
            for (int t1 = 0; t1 < 2; ++t1)
                acc_v[mt][t1] = __builtin_amdgcn_mfma_f32_16x16x32_bf16(af[mt], wv[t1], acc_v[mt][t1], 0, 0, 0);
        __builtin_amdgcn_s_setprio(0);
    }
    unsigned vpk[4][2][2];
#pragma unroll
    for (int t1 = 0; t1 < 2; ++t1)
#pragma unroll
        for (int mt = 0; mt < 4; ++mt) {
            vpk[mt][t1][0] = pk2(acc_v[mt][t1][0], acc_v[mt][t1][1]);
            vpk[mt][t1][1] = pk2(acc_v[mt][t1][2], acc_v[mt][t1][3]);
        }

    // ---------- phase 2b: QK-GEMM (weights as A, x as B); bias via C-init ----------
    f32x4 acc_qk[4][4];
#pragma unroll
    for (int t = 0; t < 4; ++t) {
        f32x4 b4 = *reinterpret_cast<const f32x4*>(bias2 + (t >> 1) * 128 + (2 * wave + (t & 1)) * 16 + 4 * g);
#pragma unroll
        for (int tt = 0; tt < 4; ++tt) acc_qk[t][tt] = b4;
    }
#pragma unroll
    for (int kt = 0; kt < 4; ++kt) {
        s16x8 af[4];
#pragma unroll
        for (int tt = 0; tt < 4; ++tt)
            af[tt] = *reinterpret_cast<const s16x8*>(&xt[(tt * 16 + lr) * XT_STRIDE + kt * 32 + g * 8]);
        s16x8 wq[4];
#pragma unroll
        for (int t = 0; t < 4; ++t) {
            int ot = (t >> 1) * 8 + 2 * wave + (t & 1);
            wq[t] = pkqv[(kt * 24 + ot) * 64 + lane];
        }
        __builtin_amdgcn_s_setprio(1);
#pragma unroll
        for (int t = 0; t < 4; ++t)
#pragma unroll
            for (int tt = 0; tt < 4; ++tt)
                acc_qk[t][tt] = __builtin_amdgcn_mfma_f32_16x16x32_bf16(wq[t], af[tt], acc_qk[t][tt], 0, 0, 0);
        __builtin_amdgcn_s_setprio(0);
    }
    __syncthreads(); // all xt reads done; head regions may overwrite xt

    // ---------- scatter q/k: packed b64 writes, swizzled ----------
    u16* hb = smem + wave * HEAD_SZ;
    u16* qb = hb;
    u16* kb = hb + K_OFF;
#pragma unroll
    for (int t = 0; t < 4; ++t) {
        u16* base = (t < 2) ? qb : kb;
        int c0 = (16 * (t & 1) + 4 * g) ^ qs;
#pragma unroll
        for (int tt = 0; tt < 4; ++tt) {
            uint2 w2;
            w2.x = pk2(acc_qk[t][tt][0], acc_qk[t][tt][1]);
            w2.y = pk2(acc_qk[t][tt][2], acc_qk[t][tt][3]);
            *reinterpret_cast<uint2*>(&base[(tt * 16 + lr) * 32 + c0]) = w2;
        }
    }
    asm volatile("s_waitcnt lgkmcnt(0)" ::: "memory");

    // ---------- phase 3: S^T = K.Q^T; bias(+mask) via C-init from bMv ----------
    f32x4 st[4][4];
    {
        s16x8 ak[4], bq[4];
        int rc = (g * 8) ^ qs;
#pragma unroll
        for (int mt = 0; mt < 4; ++mt)
            ak[mt] = *reinterpret_cast<const s16x8*>(&kb[(mt * 16 + lr) * 32 + rc]);
#pragma unroll
        for (int nt = 0; nt < 4; ++nt)
            bq[nt] = *reinterpret_cast<const s16x8*>(&qb[(nt * 16 + lr) * 32 + rc]);
        __builtin_amdgcn_s_setprio(1);
#pragma unroll
        for (int mt = 0; mt < 4; ++mt)
#pragma unroll
            for (int nt = 0; nt < 4; ++nt)
                st[mt][nt] = __builtin_amdgcn_mfma_f32_16x16x32_bf16(
                    ak[mt], bq[nt], bv4[(((wave * 4 + mt) * 4 + nt) * 4 + g) * 16 + lr], 0, 0, 0);
        __builtin_amdgcn_s_setprio(0);
    }
    // softmax (log2 domain, no max-subtraction; padding -1e30 -> exp2 = 0)
    float inv[4];
#pragma unroll
    for (int nt = 0; nt < 4; ++nt) {
        float s = 0.f;
#pragma unroll
        for (int mt = 0; mt < 4; ++mt)
#pragma unroll
            for (int r = 0; r < 4; ++r) {
                float e = exp2f(st[mt][nt][r]);
                st[mt][nt][r] = e;
                s += e;
            }
        s += __shfl_xor(s, 16, 64);
        s += __shfl_xor(s, 32, 64);
        inv[nt] = 1.0f / s;
    }
    // write P (unnormalized) [64 q][64 j] bf16, XOR-swizzled, over q+k region
    char* pB = reinterpret_cast<char*>(hb);
#pragma unroll
    for (int mt = 0; mt < 4; ++mt)
#pragma unroll
        for (int nt = 0; nt < 4; ++nt) {
            uint2 w2;
            w2.x = pk2(st[mt][nt][0], st[mt][nt][1]);
            w2.y = pk2(st[mt][nt][2], st[mt][nt][3]);
            int q = nt * 16 + lr;
            int off = (q * 128 + mt * 32 + g * 8) ^ ((q & 7) << 4);
            *reinterpret_cast<uint2*>(pB + off) = w2;
        }

    // issue next window's staging loads (vmem; in flight across PV+ao+proj)
    if (issueNext) {
#pragma unroll
        for (int u = 0; u < 6; ++u)
            xinN[u] = reinterpret_cast<const float4*>(xpN)[tid + u * 256];
        if (tid < 32) xinN[6] = reinterpret_cast<const float4*>(xpN)[1536 + tid];
    }
    asm volatile("s_waitcnt lgkmcnt(0)" ::: "memory"); // P visible (LDS only)

    // ---------- phase 4: transposed PV: out^T = V^T . P^T ----------
    const int srcA4 = (((lane & 16) << 1) | lr) << 2;
    const int srcB4 = srcA4 + 64;
    const bool hi32 = (lane & 32) != 0;
    f32x4 ov[2][4] = {};
    {
        s16x8 va[2][2], pbf[4][2];
#pragma unroll
        for (int t1 = 0; t1 < 2; ++t1)
#pragma unroll
            for (int kk = 0; kk < 2; ++kk) {
                union { s16x8 v; unsigned u[4]; } tmp;
#pragma unroll
                for (int w = 0; w < 4; ++w) {
                    int src = (w < 2) ? srcA4 : srcB4;
                    unsigned lo = (unsigned)__builtin_amdgcn_ds_bpermute(src, (int)vpk[2 * kk][t1][w & 1]);
                    unsigned hh = (unsigned)__builtin_amdgcn_ds_bpermute(src, (int)vpk[2 * kk + 1][t1][w & 1]);
                    tmp.u[w] = hi32 ? hh : lo;
                }
                va[t1][kk] = tmp.v;
            }
#pragma unroll
        for (int nt = 0; nt < 4; ++nt)
#pragma unroll
            for (int kk = 0; kk < 2; ++kk) {
                int off = (((nt * 16 + lr) * 128) + kk * 64 + g * 16) ^ ((lr & 7) << 4);
                pbf[nt][kk] = *reinterpret_cast<const s16x8*>(pB + off);
            }
        __builtin_amdgcn_s_setprio(1);
#pragma unroll
        for (int t1 = 0; t1 < 2; ++t1)
#pragma unroll
            for (int nt = 0; nt < 4; ++nt)
#pragma unroll
                for (int kk = 0; kk < 2; ++kk)
                    ov[t1][nt] = __builtin_amdgcn_mfma_f32_16x16x32_bf16(va[t1][kk], pbf[nt][kk], ov[t1][nt], 0, 0, 0);
        __builtin_amdgcn_s_setprio(0);
    }
#pragma unroll
    for (int t1 = 0; t1 < 2; ++t1)
#pragma unroll
        for (int nt = 0; nt < 4; ++nt)
#pragma unroll
            for (int r = 0; r < 4; ++r) ov[t1][nt][r] *= inv[nt];

    // proj A-fragments (global)
    s16x8 pfr[4][2];
#pragma unroll
    for (int kt = 0; kt < 4; ++kt)
#pragma unroll
        for (int t = 0; t < 2; ++t)
            pfr[kt][t] = pkpv[(kt * 8 + 2 * wave + t) * 64 + lane];

    // ao chunk into OWN region
#pragma unroll
    for (int t1 = 0; t1 < 2; ++t1)
#pragma unroll
        for (int nt = 0; nt < 4; ++nt) {
            uint2 w2;
            w2.x = pk2(ov[t1][nt][0], ov[t1][nt][1]);
            w2.y = pk2(ov[t1][nt][2], ov[t1][nt][3]);
            int lg = 2 * t1 + (g >> 1);
            int off = (nt * 16 + lr) * 32 + (((lg << 3) ^ qs)) + ((g & 1) << 2);
            *reinterpret_cast<uint2*>(&hb[off]) = w2;
        }
    __syncthreads(); // all ao chunks visible

    // ---------- phase 5: proj^T GEMM; bias via C-init ----------
    f32x4 pacc[2][4];
#pragma unroll
    for (int t = 0; t < 2; ++t) {
        f32x4 pb4 = *reinterpret_cast<const f32x4*>(proj_b + (2 * wave + t) * 16 + 4 * g);
#pragma unroll
        for (int tt = 0; tt < 4; ++tt) pacc[t][tt] = pb4;
    }
#pragma unroll
    for (int kt = 0; kt < 4; ++kt) {
        s16x8 af2[4];
#pragma unroll
        for (int tt = 0; tt < 4; ++tt)
            af2[tt] = *reinterpret_cast<const s16x8*>(&smem[kt * HEAD_SZ + (tt * 16 + lr) * 32 + ((g * 8) ^ qs)]);
        __builtin_amdgcn_s_setprio(1);
#pragma unroll
        for (int t = 0; t < 2; ++t)
#pragma unroll
            for (int tt = 0; tt < 4; ++tt)
                pacc[t][tt] = __builtin_amdgcn_mfma_f32_16x16x32_bf16(pfr[kt][t], af2[tt], pacc[t][tt], 0, 0, 0);
        __builtin_amdgcn_s_setprio(0);
    }
    // stores: tt outer / t inner so the two 64B halves of each 128B line are adjacent
#pragma unroll
    for (int tt = 0; tt < 4; ++tt) {
        int tok = tt * 16 + lr;
        if (tok < NTOK) {
#pragma unroll
            for (int t = 0; t < 2; ++t) {
                int oc0 = (2 * wave + t) * 16 + 4 * g;
                *reinterpret_cast<f32x4*>(outp + (size_t)tok * CDIM + oc0) = pacc[t][tt];
            }
        }
    }
}

__global__ __launch_bounds__(256, 4) void winattn_kernel(
    const float* __restrict__ x, const float* __restrict__ bias2,
    const float* __restrict__ proj_b,
    const u16* __restrict__ pkq, const u16* __restrict__ pkp,
    const float* __restrict__ bMv, float* __restrict__ out) {
    __shared__ __align__(16) u16 smem[LDS_ELEMS];
    const int tid = threadIdx.x;
    const int wave = tid >> 6, lane = tid & 63;
    const int g = lane >> 4, lr = lane & 15;
    const int qs = ((lr >> 1) & 3) << 3;

    const s16x8* pkqv = reinterpret_cast<const s16x8*>(pkq);
    const s16x8* pkpv = reinterpret_cast<const s16x8*>(pkp);
    const f32x4* bv4 = reinterpret_cast<const f32x4*>(bMv);

    const int b0 = blockIdx.x * 2;
    const float* xpA = x + (size_t)b0 * (NTOK * CDIM);
    const float* xpB = xpA + NTOK * CDIM;
    float* outA = out + (size_t)b0 * (NTOK * CDIM);
    float* outB = outA + NTOK * CDIM;

    // ---------- stage window A ----------
    {
        float4 xinA[7];
#pragma unroll
        for (int u = 0; u < 6; ++u)
            xinA[u] = reinterpret_cast<const float4*>(xpA)[tid + u * 256];
        if (tid < 32) xinA[6] = reinterpret_cast<const float4*>(xpA)[1536 + tid];
        xt_write(smem, xinA, tid);
    }
    __syncthreads();

    // ---------- window A (issues B's loads mid-flight) ----------
    float4 xinB[7];
    win_body(smem, outA, bias2, proj_b, pkqv, pkpv, bv4,
             xpB, xinB, true, wave, lane, g, lr, qs, tid);

    __syncthreads();          // all waves done with A's proj LDS reads
    xt_write(smem, xinB, tid); // xt region fully dead; rewrite incl. zeros
    __syncthreads();

    // ---------- window B ----------
    win_body(smem, outB, bias2, proj_b, pkqv, pkpv, bv4,
             nullptr, nullptr, false, wave, lane, g, lr, qs, tid);
}

extern "C" void kernel_launch(void* const* d_in, const int* in_sizes, int n_in,
                              void* d_out, int out_size, void* d_ws, size_t ws_size,
                              hipStream_t stream) {
    const float* x      = (const float*)d_in[0];
    const float* qkv_w  = (const float*)d_in[1];
    const float* qkv_b  = (const float*)d_in[2];
    const float* proj_w = (const float*)d_in[3];
    const float* proj_b = (const float*)d_in[4];
    const float* rpb    = (const float*)d_in[5];
    const int*   rpi    = (const int*)d_in[6];
    float* out = (float*)d_out;

    u16*   pkq   = (u16*)d_ws;                        // 49152 bf16 (98304 B)
    u16*   pkp   = pkq + 49152;                       // 16384 bf16 (32768 B)
    float* bMv   = (float*)((char*)d_ws + 131072);    // 16384 fp32 (65536 B)
    float* bias2 = (float*)((char*)d_ws + 196608);    // 384 fp32 (1536 B)

    prep_kernel<<<322, 256, 0, stream>>>(qkv_w, proj_w, rpb, rpi, qkv_b, pkq, pkp, bMv, bias2);
    winattn_kernel<<<NWIN / 2, 256, 0, stream>>>(x, bias2, proj_b, pkq, pkp, bMv, out);
}

// Round 14
// 93.151 us; speedup vs baseline: 2.2168x; 2.2168x over previous
//
#include <hip/hip_runtime.h>
#include <hip/hip_bf16.h>

typedef __attribute__((ext_vector_type(8))) short s16x8;
typedef __attribute__((ext_vector_type(4))) float f32x4;
typedef unsigned short u16;

#define NTOK 49
#define CDIM 128
#define NWIN 4096
#define LOG2E 1.4426950408889634f
#define SCL (0.17677669529663687f * LOG2E)  // 32^-0.5 * log2(e), folded into q weights+bias

// LDS plan (u16 units), r14: xt NO LONGER aliases head regions.
//  xt [64][136] at 0 (8704 u16) -- persistent all window
//  head region (8704 + wave*4096): q [64][32] swz, k at +2048
//    after S^T reads: P [64][64] bytes XOR-swz; after PV: ao chunk [64][32] swz
//  total 25088 u16 = 50176 B -> 3 blocks/CU (measured occupancy was ~3.2 blocks
//  at 32KB anyway -- residency is scheduler-limited, not LDS-limited, r8 vs r5)
// De-aliasing deletes the post-QKV barrier: scatter/S^T/softmax/P/PV are wave-local.
// Barriers per window: 2 (post-staging, post-ao).
// launch_bounds (256,4): VGPR cap 128 (compiles 64, no spill).
// r7: (256,5) -> 48 VGPR + spill. r6: (256,8) -> 120 VGPR. r11/r13: cross-phase
// register prefetch/hoist ALWAYS spills at this budget (0-for-3) -- don't.
#define XT_STRIDE 136
#define HEADS_OFF 8704
#define HEAD_SZ 4096
#define K_OFF 2048
#define LDS_ELEMS 25088

__device__ __forceinline__ u16 f2bf(float f) {
    __hip_bfloat16 h = __float2bfloat16(f);
    return __builtin_bit_cast(u16, h);
}
__device__ __forceinline__ unsigned pk2(float a, float b) {
    return (unsigned)f2bf(a) | ((unsigned)f2bf(b) << 16);
}

// pkq: [(kt*24+ot)*64+lane]*8+r = qkv_w[o=ot*16+lr][c=kt*32+8g+r]; q rows (o<128) pre-scaled by SCL
// pkp: same layout, 8 o-tiles   = proj_w[o][c]
// bMv: [h][mt][nt][g][lr][r] = bias[q=16nt+lr][j=16mt+4g+r]*LOG2E; -1e30 where q or j >= 49
// bias2: [384] = qkv_b, q part (o<128) pre-scaled by SCL
__global__ void prep_kernel(const float* __restrict__ qkv_w,
                            const float* __restrict__ proj_w,
                            const float* __restrict__ rpb,
                            const int* __restrict__ rpi,
                            const float* __restrict__ qkv_b,
                            u16* __restrict__ pkq, u16* __restrict__ pkp,
                            float* __restrict__ bMv, float* __restrict__ bias2) {
    int idx = blockIdx.x * blockDim.x + threadIdx.x;
    if (idx < 49152) {
        int r = idx & 7, lane = (idx >> 3) & 63, tile = idx >> 9;
        int ot = tile % 24, kt = tile / 24;
        int o = ot * 16 + (lane & 15);
        int k = kt * 32 + ((lane >> 4) << 3) + r;
        float w = qkv_w[o * CDIM + k];
        if (o < 128) w *= SCL;
        pkq[idx] = f2bf(w);
    } else if (idx < 65536) {
        int i2 = idx - 49152;
        int r = i2 & 7, lane = (i2 >> 3) & 63, tile = i2 >> 9;
        int ot = tile & 7, kt = tile >> 3;
        int o = ot * 16 + (lane & 15);
        int k = kt * 32 + ((lane >> 4) << 3) + r;
        pkp[i2] = f2bf(proj_w[o * CDIM + k]);
    } else if (idx < 81920) {
        int i = idx - 65536;
        int r = i & 3, lr = (i >> 2) & 15, g = (i >> 6) & 3;
        int nt = (i >> 8) & 3, mt = (i >> 10) & 3, h = i >> 12;
        int q = nt * 16 + lr, j = mt * 16 + 4 * g + r;
        bMv[i] = (q < NTOK && j < NTOK) ? rpb[rpi[q * NTOK + j] * 4 + h] * LOG2E : -1e30f;
    } else if (idx < 82304) {
        int o = idx - 81920;
        bias2[o] = qkv_b[o] * (o < 128 ? SCL : 1.0f);
    }
}

__global__ __launch_bounds__(256, 4) void winattn_kernel(
    const float* __restrict__ x, const float* __restrict__ bias2,
    const float* __restrict__ proj_b,
    const u16* __restrict__ pkq, const u16* __restrict__ pkp,
    const float* __restrict__ bMv, float* __restrict__ out) {
    __shared__ __align__(16) u16 smem[LDS_ELEMS];
    const int b = blockIdx.x;
    const int tid = threadIdx.x;
    const int wave = tid >> 6, lane = tid & 63;
    const int g = lane >> 4, lr = lane & 15;
    const int qs = ((lr >> 1) & 3) << 3; // column XOR swizzle (u16 units, 16B granules)

    u16* xt = smem; // [64][136], persistent (no aliasing this round)

    // ---------- phase 1: x -> bf16 LDS, issue-all-loads-first (T14 split) ----------
    const float* xp = x + (size_t)b * (NTOK * CDIM);
    float4 xin[7];
#pragma unroll
    for (int u = 0; u < 6; ++u)
        xin[u] = reinterpret_cast<const float4*>(xp)[tid + u * 256];
    if (tid < 32) xin[6] = reinterpret_cast<const float4*>(xp)[1536 + tid];
#pragma unroll
    for (int u = 0; u < 6; ++u) {
        int lin = (tid + u * 256) * 4;
        int i = lin >> 7, c = lin & 127;
        uint2 pkv;
        pkv.x = pk2(xin[u].x, xin[u].y);
        pkv.y = pk2(xin[u].z, xin[u].w);
        *reinterpret_cast<uint2*>(&xt[i * XT_STRIDE + c]) = pkv;
    }
    if (tid < 32) {
        int lin = (1536 + tid) * 4;
        int i = lin >> 7, c = lin & 127;
        uint2 pkv;
        pkv.x = pk2(xin[6].x, xin[6].y);
        pkv.y = pk2(xin[6].z, xin[6].w);
        *reinterpret_cast<uint2*>(&xt[i * XT_STRIDE + c]) = pkv;
    }
    {
        const uint2 z2 = {0u, 0u};
#pragma unroll
        for (int u = 0; u < 2; ++u)
            *reinterpret_cast<uint2*>(&xt[NTOK * XT_STRIDE + (tid + u * 256) * 4]) = z2;
    }
    __syncthreads(); // barrier 1: xt visible to all waves

    const s16x8* pkqv = reinterpret_cast<const s16x8*>(pkq);

    // ---------- phase 2a: V-GEMM (x as A, weights as B); bias via C-init ----------
    f32x4 acc_v[4][2];
#pragma unroll
    for (int t1 = 0; t1 < 2; ++t1) {
        float vb = bias2[256 + (2 * wave + t1) * 16 + lr];
#pragma unroll
        for (int mt = 0; mt < 4; ++mt) acc_v[mt][t1] = (f32x4){vb, vb, vb, vb};
    }
#pragma unroll
    for (int kt = 0; kt < 4; ++kt) {
        s16x8 af[4];
#pragma unroll
        for (int tt = 0; tt < 4; ++tt)
            af[tt] = *reinterpret_cast<const s16x8*>(&xt[(tt * 16 + lr) * XT_STRIDE + kt * 32 + g * 8]);
        s16x8 wv[2];
#pragma unroll
        for (int t1 = 0; t1 < 2; ++t1)
            wv[t1] = pkqv[(kt * 24 + 16 + 2 * wave + t1) * 64 + lane];
        __builtin_amdgcn_s_setprio(1);
#pragma unroll
        for (int mt = 0; mt < 4; ++mt)
#pragma unroll
            for (int t1 = 0; t1 < 2; ++t1)
                acc_v[mt][t1] = __builtin_amdgcn_mfma_f32_16x16x32_bf16(af[mt], wv[t1], acc_v[mt][t1], 0, 0, 0);
        __builtin_amdgcn_s_setprio(0);
    }
    unsigned vpk[4][2][2];
#pragma unroll
    for (int t1 = 0; t1 < 2; ++t1)
#pragma unroll
        for (int mt = 0; mt < 4; ++mt) {
            vpk[mt][t1][0] = pk2(acc_v[mt][t1][0], acc_v[mt][t1][1]);
            vpk[mt][t1][1] = pk2(acc_v[mt][t1][2], acc_v[mt][t1][3]);
        }

    // ---------- phase 2b: QK-GEMM (weights as A, x as B); bias via C-init ----------
    f32x4 acc_qk[4][4];
#pragma unroll
    for (int t = 0; t < 4; ++t) {
        f32x4 b4 = *reinterpret_cast<const f32x4*>(bias2 + (t >> 1) * 128 + (2 * wave + (t & 1)) * 16 + 4 * g);
#pragma unroll
        for (int tt = 0; tt < 4; ++tt) acc_qk[t][tt] = b4;
    }
#pragma unroll
    for (int kt = 0; kt < 4; ++kt) {
        s16x8 af[4];
#pragma unroll
        for (int tt = 0; tt < 4; ++tt)
            af[tt] = *reinterpret_cast<const s16x8*>(&xt[(tt * 16 + lr) * XT_STRIDE + kt * 32 + g * 8]);
        s16x8 wq[4];
#pragma unroll
        for (int t = 0; t < 4; ++t) {
            int ot = (t >> 1) * 8 + 2 * wave + (t & 1);
            wq[t] = pkqv[(kt * 24 + ot) * 64 + lane];
        }
        __builtin_amdgcn_s_setprio(1);
#pragma unroll
        for (int t = 0; t < 4; ++t)
#pragma unroll
            for (int tt = 0; tt < 4; ++tt)
                acc_qk[t][tt] = __builtin_amdgcn_mfma_f32_16x16x32_bf16(wq[t], af[tt], acc_qk[t][tt], 0, 0, 0);
        __builtin_amdgcn_s_setprio(0);
    }
    // NO barrier: heads no longer alias xt; everything below is wave-local until ao.

    // ---------- scatter q/k: packed b64 writes, swizzled (own head region) ----------
    u16* hb = smem + HEADS_OFF + wave * HEAD_SZ;
    u16* qb = hb;
    u16* kb = hb + K_OFF;
#pragma unroll
    for (int t = 0; t < 4; ++t) {
        u16* base = (t < 2) ? qb : kb;
        int c0 = (16 * (t & 1) + 4 * g) ^ qs;
#pragma unroll
        for (int tt = 0; tt < 4; ++tt) {
            uint2 w2;
            w2.x = pk2(acc_qk[t][tt][0], acc_qk[t][tt][1]);
            w2.y = pk2(acc_qk[t][tt][2], acc_qk[t][tt][3]);
            *reinterpret_cast<uint2*>(&base[(tt * 16 + lr) * 32 + c0]) = w2;
        }
    }
    asm volatile("s_waitcnt lgkmcnt(0)" ::: "memory");

    // ---------- phase 3: S^T = K.Q^T; bias(+mask) via C-init from bMv ----------
    const f32x4* bv4 = reinterpret_cast<const f32x4*>(bMv);
    f32x4 st[4][4];
    {
        s16x8 ak[4], bq[4];
        int rc = (g * 8) ^ qs;
#pragma unroll
        for (int mt = 0; mt < 4; ++mt)
            ak[mt] = *reinterpret_cast<const s16x8*>(&kb[(mt * 16 + lr) * 32 + rc]);
#pragma unroll
        for (int nt = 0; nt < 4; ++nt)
            bq[nt] = *reinterpret_cast<const s16x8*>(&qb[(nt * 16 + lr) * 32 + rc]);
        __builtin_amdgcn_s_setprio(1);
#pragma unroll
        for (int mt = 0; mt < 4; ++mt)
#pragma unroll
            for (int nt = 0; nt < 4; ++nt)
                st[mt][nt] = __builtin_amdgcn_mfma_f32_16x16x32_bf16(
                    ak[mt], bq[nt], bv4[(((wave * 4 + mt) * 4 + nt) * 4 + g) * 16 + lr], 0, 0, 0);
        __builtin_amdgcn_s_setprio(0);
    }
    // softmax (log2 domain, no max-subtraction; padding -1e30 -> exp2 = 0)
    float inv[4];
#pragma unroll
    for (int nt = 0; nt < 4; ++nt) {
        float s = 0.f;
#pragma unroll
        for (int mt = 0; mt < 4; ++mt)
#pragma unroll
            for (int r = 0; r < 4; ++r) {
                float e = exp2f(st[mt][nt][r]);
                st[mt][nt][r] = e;
                s += e;
            }
        s += __shfl_xor(s, 16, 64);
        s += __shfl_xor(s, 32, 64);
        inv[nt] = 1.0f / s;
    }
    // write P (unnormalized) [64 q][64 j] bf16, XOR-swizzled, over q+k region
    char* pB = reinterpret_cast<char*>(hb);
#pragma unroll
    for (int mt = 0; mt < 4; ++mt)
#pragma unroll
        for (int nt = 0; nt < 4; ++nt) {
            uint2 w2;
            w2.x = pk2(st[mt][nt][0], st[mt][nt][1]);
            w2.y = pk2(st[mt][nt][2], st[mt][nt][3]);
            int q = nt * 16 + lr;
            int off = (q * 128 + mt * 32 + g * 8) ^ ((q & 7) << 4);
            *reinterpret_cast<uint2*>(pB + off) = w2;
        }
    asm volatile("s_waitcnt lgkmcnt(0)" ::: "memory");

    // ---------- phase 4: transposed PV: out^T = V^T . P^T ----------
    const int srcA4 = (((lane & 16) << 1) | lr) << 2;
    const int srcB4 = srcA4 + 64;
    const bool hi32 = (lane & 32) != 0;
    f32x4 ov[2][4] = {};
    {
        s16x8 va[2][2], pbf[4][2];
#pragma unroll
        for (int t1 = 0; t1 < 2; ++t1)
#pragma unroll
            for (int kk = 0; kk < 2; ++kk) {
                union { s16x8 v; unsigned u[4]; } tmp;
#pragma unroll
                for (int w = 0; w < 4; ++w) {
                    int src = (w < 2) ? srcA4 : srcB4;
                    unsigned lo = (unsigned)__builtin_amdgcn_ds_bpermute(src, (int)vpk[2 * kk][t1][w & 1]);
                    unsigned hh = (unsigned)__builtin_amdgcn_ds_bpermute(src, (int)vpk[2 * kk + 1][t1][w & 1]);
                    tmp.u[w] = hi32 ? hh : lo;
                }
                va[t1][kk] = tmp.v;
            }
#pragma unroll
        for (int nt = 0; nt < 4; ++nt)
#pragma unroll
            for (int kk = 0; kk < 2; ++kk) {
                int off = (((nt * 16 + lr) * 128) + kk * 64 + g * 16) ^ ((lr & 7) << 4);
                pbf[nt][kk] = *reinterpret_cast<const s16x8*>(pB + off);
            }
        __builtin_amdgcn_s_setprio(1);
#pragma unroll
        for (int t1 = 0; t1 < 2; ++t1)
#pragma unroll
            for (int nt = 0; nt < 4; ++nt)
#pragma unroll
                for (int kk = 0; kk < 2; ++kk)
                    ov[t1][nt] = __builtin_amdgcn_mfma_f32_16x16x32_bf16(va[t1][kk], pbf[nt][kk], ov[t1][nt], 0, 0, 0);
        __builtin_amdgcn_s_setprio(0);
    }
    // deferred normalization (per q-row scalar)
#pragma unroll
    for (int t1 = 0; t1 < 2; ++t1)
#pragma unroll
        for (int nt = 0; nt < 4; ++nt)
#pragma unroll
            for (int r = 0; r < 4; ++r) ov[t1][nt][r] *= inv[nt];

    // proj A-fragments (global)
    s16x8 pfr[4][2];
    const s16x8* pkpv = reinterpret_cast<const s16x8*>(pkp);
#pragma unroll
    for (int kt = 0; kt < 4; ++kt)
#pragma unroll
        for (int t = 0; t < 2; ++t)
            pfr[kt][t] = pkpv[(kt * 8 + 2 * wave + t) * 64 + lane];

    // ---------- ao chunk into OWN region ----------
#pragma unroll
    for (int t1 = 0; t1 < 2; ++t1)
#pragma unroll
        for (int nt = 0; nt < 4; ++nt) {
            uint2 w2;
            w2.x = pk2(ov[t1][nt][0], ov[t1][nt][1]);
            w2.y = pk2(ov[t1][nt][2], ov[t1][nt][3]);
            int lg = 2 * t1 + (g >> 1);
            int off = (nt * 16 + lr) * 32 + (((lg << 3) ^ qs)) + ((g & 1) << 2);
            *reinterpret_cast<uint2*>(&hb[off]) = w2;
        }
    __syncthreads(); // barrier 2: all ao chunks visible

    // ---------- phase 5: proj^T GEMM (weights as A, ao as B); bias via C-init ----------
    f32x4 pacc[2][4];
#pragma unroll
    for (int t = 0; t < 2; ++t) {
        f32x4 pb4 = *reinterpret_cast<const f32x4*>(proj_b + (2 * wave + t) * 16 + 4 * g);
#pragma unroll
        for (int tt = 0; tt < 4; ++tt) pacc[t][tt] = pb4;
    }
#pragma unroll
    for (int kt = 0; kt < 4; ++kt) {
        s16x8 af2[4];
#pragma unroll
        for (int tt = 0; tt < 4; ++tt)
            af2[tt] = *reinterpret_cast<const s16x8*>(
                &smem[HEADS_OFF + kt * HEAD_SZ + (tt * 16 + lr) * 32 + ((g * 8) ^ qs)]);
        __builtin_amdgcn_s_setprio(1);
#pragma unroll
        for (int t = 0; t < 2; ++t)
#pragma unroll
            for (int tt = 0; tt < 4; ++tt)
                pacc[t][tt] = __builtin_amdgcn_mfma_f32_16x16x32_bf16(pfr[kt][t], af2[tt], pacc[t][tt], 0, 0, 0);
        __builtin_amdgcn_s_setprio(0);
    }
    // stores: tt outer / t inner so the two 64B halves of each 128B line are adjacent
    float* outp = out + (size_t)b * (NTOK * CDIM);
#pragma unroll
    for (int tt = 0; tt < 4; ++tt) {
        int tok = tt * 16 + lr;
        if (tok < NTOK) {
#pragma unroll
            for (int t = 0; t < 2; ++t) {
                int oc0 = (2 * wave + t) * 16 + 4 * g;
                *reinterpret_cast<f32x4*>(outp + (size_t)tok * CDIM + oc0) = pacc[t][tt];
            }
        }
    }
}

extern "C" void kernel_launch(void* const* d_in, const int* in_sizes, int n_in,
                              void* d_out, int out_size, void* d_ws, size_t ws_size,
                              hipStream_t stream) {
    const float* x      = (const float*)d_in[0];
    const float* qkv_w  = (const float*)d_in[1];
    const float* qkv_b  = (const float*)d_in[2];
    const float* proj_w = (const float*)d_in[3];
    const float* proj_b = (const float*)d_in[4];
    const float* rpb    = (const float*)d_in[5];
    const int*   rpi    = (const int*)d_in[6];
    float* out = (float*)d_out;

    u16*   pkq   = (u16*)d_ws;                        // 49152 bf16 (98304 B)
    u16*   pkp   = pkq + 49152;                       // 16384 bf16 (32768 B)
    float* bMv   = (float*)((char*)d_ws + 131072);    // 16384 fp32 (65536 B)
    float* bias2 = (float*)((char*)d_ws + 196608);    // 384 fp32 (1536 B)

    prep_kernel<<<322, 256, 0, stream>>>(qkv_w, proj_w, rpb, rpi, qkv_b, pkq, pkp, bMv, bias2);
    winattn_kernel<<<NWIN, 256, 0, stream>>>(x, bias2, proj_b, pkq, pkp, bMv, out);
}

// Round 15
// 83.531 us; speedup vs baseline: 2.4721x; 1.1152x over previous
//
#include <hip/hip_runtime.h>
#include <hip/hip_bf16.h>

typedef __attribute__((ext_vector_type(8))) short s16x8;
typedef __attribute__((ext_vector_type(4))) float f32x4;
typedef unsigned short u16;

#define NTOK 49
#define CDIM 128
#define NWIN 4096
#define LOG2E 1.4426950408889634f
#define SCL (0.17677669529663687f * LOG2E)  // 32^-0.5 * log2(e), folded into q weights+bias

// FINAL (r15 = r12, measured best: 83.8 us bench / ~100 us rocprof).
// LDS plan (u16 units). 4 per-wave head regions of 4096 -> 16384 u16 = 32.0 KB.
//  phase 1-2: xt [64][136] at 0 (8704 u16; aliases regions 0/1+part of 2, barrier-protected)
//  region (wave*4096): q [64][32] swz at 0, k [64][32] swz at 2048
//    after S^T reads: P [64][64] bytes XOR-swz at 0 (whole region)
//    after PV reads:  ao chunk [64 rows][32 cols] swz at 0 (own region -> no pre-barrier)
// launch_bounds (256,4): VGPR cap 128 (compiles to 64, no spill).
// Tried and rejected (counter evidence):
//  r6 (256,8): backend gives up, 120 VGPR, occ 21%.  r7 (256,5): 48 VGPR + scratch spill.
//  r11/r13: cross-phase register prefetch/hoist spills at 64-VGPR budget (0-for-3).
//  r14: de-aliased xt (50KB LDS): barrier removed but occupancy 38->21%, net -8%.
//  r3: A-frags direct from global: uncoalesced 512B-stride, FETCH 2x, net -35%.
#define XT_STRIDE 136
#define HEAD_SZ 4096
#define K_OFF 2048
#define LDS_ELEMS 16384

__device__ __forceinline__ u16 f2bf(float f) {
    __hip_bfloat16 h = __float2bfloat16(f);
    return __builtin_bit_cast(u16, h);
}
__device__ __forceinline__ unsigned pk2(float a, float b) {
    return (unsigned)f2bf(a) | ((unsigned)f2bf(b) << 16);
}

// pkq: [(kt*24+ot)*64+lane]*8+r = qkv_w[o=ot*16+lr][c=kt*32+8g+r]; q rows (o<128) pre-scaled by SCL
// pkp: same layout, 8 o-tiles   = proj_w[o][c]
// bMv: [h][mt][nt][g][lr][r] = bias[q=16nt+lr][j=16mt+4g+r]*LOG2E; -1e30 where q or j >= 49
// bias2: [384] = qkv_b, q part (o<128) pre-scaled by SCL
__global__ void prep_kernel(const float* __restrict__ qkv_w,
                            const float* __restrict__ proj_w,
                            const float* __restrict__ rpb,
                            const int* __restrict__ rpi,
                            const float* __restrict__ qkv_b,
                            u16* __restrict__ pkq, u16* __restrict__ pkp,
                            float* __restrict__ bMv, float* __restrict__ bias2) {
    int idx = blockIdx.x * blockDim.x + threadIdx.x;
    if (idx < 49152) {
        int r = idx & 7, lane = (idx >> 3) & 63, tile = idx >> 9;
        int ot = tile % 24, kt = tile / 24;
        int o = ot * 16 + (lane & 15);
        int k = kt * 32 + ((lane >> 4) << 3) + r;
        float w = qkv_w[o * CDIM + k];
        if (o < 128) w *= SCL;
        pkq[idx] = f2bf(w);
    } else if (idx < 65536) {
        int i2 = idx - 49152;
        int r = i2 & 7, lane = (i2 >> 3) & 63, tile = i2 >> 9;
        int ot = tile & 7, kt = tile >> 3;
        int o = ot * 16 + (lane & 15);
        int k = kt * 32 + ((lane >> 4) << 3) + r;
        pkp[i2] = f2bf(proj_w[o * CDIM + k]);
    } else if (idx < 81920) {
        int i = idx - 65536;
        int r = i & 3, lr = (i >> 2) & 15, g = (i >> 6) & 3;
        int nt = (i >> 8) & 3, mt = (i >> 10) & 3, h = i >> 12;
        int q = nt * 16 + lr, j = mt * 16 + 4 * g + r;
        bMv[i] = (q < NTOK && j < NTOK) ? rpb[rpi[q * NTOK + j] * 4 + h] * LOG2E : -1e30f;
    } else if (idx < 82304) {
        int o = idx - 81920;
        bias2[o] = qkv_b[o] * (o < 128 ? SCL : 1.0f);
    }
}

__global__ __launch_bounds__(256, 4) void winattn_kernel(
    const float* __restrict__ x, const float* __restrict__ bias2,
    const float* __restrict__ proj_b,
    const u16* __restrict__ pkq, const u16* __restrict__ pkp,
    const float* __restrict__ bMv, float* __restrict__ out) {
    __shared__ __align__(16) u16 smem[LDS_ELEMS];
    const int b = blockIdx.x;
    const int tid = threadIdx.x;
    const int wave = tid >> 6, lane = tid & 63;
    const int g = lane >> 4, lr = lane & 15;
    const int qs = ((lr >> 1) & 3) << 3; // column XOR swizzle (u16 units, 16B granules)

    u16* xt = smem; // [64][136]

    // ---------- phase 1: x -> bf16 LDS, issue-all-loads-first (T14 split) ----------
    // 1568 float4 total = 6*256 uniform + 32 tail (tid<32)
    const float* xp = x + (size_t)b * (NTOK * CDIM);
    float4 xin[7];
#pragma unroll
    for (int u = 0; u < 6; ++u)
        xin[u] = reinterpret_cast<const float4*>(xp)[tid + u * 256];
    if (tid < 32) xin[6] = reinterpret_cast<const float4*>(xp)[1536 + tid];
#pragma unroll
    for (int u = 0; u < 6; ++u) {
        int lin = (tid + u * 256) * 4;
        int i = lin >> 7, c = lin & 127;
        uint2 pkv;
        pkv.x = pk2(xin[u].x, xin[u].y);
        pkv.y = pk2(xin[u].z, xin[u].w);
        *reinterpret_cast<uint2*>(&xt[i * XT_STRIDE + c]) = pkv;
    }
    if (tid < 32) {
        int lin = (1536 + tid) * 4;
        int i = lin >> 7, c = lin & 127;
        uint2 pkv;
        pkv.x = pk2(xin[6].x, xin[6].y);
        pkv.y = pk2(xin[6].z, xin[6].w);
        *reinterpret_cast<uint2*>(&xt[i * XT_STRIDE + c]) = pkv;
    }
    {
        const uint2 z2 = {0u, 0u};
#pragma unroll
        for (int u = 0; u < 2; ++u)
            *reinterpret_cast<uint2*>(&xt[NTOK * XT_STRIDE + (tid + u * 256) * 4]) = z2;
    }
    __syncthreads();

    const s16x8* pkqv = reinterpret_cast<const s16x8*>(pkq);

    // ---------- phase 2a: V-GEMM (x as A, weights as B); bias via C-init ----------
    // acc_v[mt][t1][r] = V[tok=16mt+4g+r][d=16t1+lr]
    f32x4 acc_v[4][2];
#pragma unroll
    for (int t1 = 0; t1 < 2; ++t1) {
        float vb = bias2[256 + (2 * wave + t1) * 16 + lr];
#pragma unroll
        for (int mt = 0; mt < 4; ++mt) acc_v[mt][t1] = (f32x4){vb, vb, vb, vb};
    }
#pragma unroll
    for (int kt = 0; kt < 4; ++kt) {
        s16x8 af[4];
#pragma unroll
        for (int tt = 0; tt < 4; ++tt)
            af[tt] = *reinterpret_cast<const s16x8*>(&xt[(tt * 16 + lr) * XT_STRIDE + kt * 32 + g * 8]);
        s16x8 wv[2];
#pragma unroll
        for (int t1 = 0; t1 < 2; ++t1)
            wv[t1] = pkqv[(kt * 24 + 16 + 2 * wave + t1) * 64 + lane];
        __builtin_amdgcn_s_setprio(1);
#pragma unroll
        for (int mt = 0; mt < 4; ++mt)
#pragma unroll
            for (int t1 = 0; t1 < 2; ++t1)
                acc_v[mt][t1] = __builtin_amdgcn_mfma_f32_16x16x32_bf16(af[mt], wv[t1], acc_v[mt][t1], 0, 0, 0);
        __builtin_amdgcn_s_setprio(0);
    }
    unsigned vpk[4][2][2];
#pragma unroll
    for (int t1 = 0; t1 < 2; ++t1)
#pragma unroll
        for (int mt = 0; mt < 4; ++mt) {
            vpk[mt][t1][0] = pk2(acc_v[mt][t1][0], acc_v[mt][t1][1]);
            vpk[mt][t1][1] = pk2(acc_v[mt][t1][2], acc_v[mt][t1][3]);
        }

    // ---------- phase 2b: QK-GEMM (weights as A, x as B); bias via C-init ----------
    // acc_qk[t][tt][r] = QKV[o=ot*16+4g+r][tok=16tt+lr], ot = (t>>1)*8+2w+(t&1); q pre-scaled
    f32x4 acc_qk[4][4];
#pragma unroll
    for (int t = 0; t < 4; ++t) {
        f32x4 b4 = *reinterpret_cast<const f32x4*>(bias2 + (t >> 1) * 128 + (2 * wave + (t & 1)) * 16 + 4 * g);
#pragma unroll
        for (int tt = 0; tt < 4; ++tt) acc_qk[t][tt] = b4;
    }
#pragma unroll
    for (int kt = 0; kt < 4; ++kt) {
        s16x8 af[4];
#pragma unroll
        for (int tt = 0; tt < 4; ++tt)
            af[tt] = *reinterpret_cast<const s16x8*>(&xt[(tt * 16 + lr) * XT_STRIDE + kt * 32 + g * 8]);
        s16x8 wq[4];
#pragma unroll
        for (int t = 0; t < 4; ++t) {
            int ot = (t >> 1) * 8 + 2 * wave + (t & 1);
            wq[t] = pkqv[(kt * 24 + ot) * 64 + lane];
        }
        __builtin_amdgcn_s_setprio(1);
#pragma unroll
        for (int t = 0; t < 4; ++t)
#pragma unroll
            for (int tt = 0; tt < 4; ++tt)
                acc_qk[t][tt] = __builtin_amdgcn_mfma_f32_16x16x32_bf16(wq[t], af[tt], acc_qk[t][tt], 0, 0, 0);
        __builtin_amdgcn_s_setprio(0);
    }
    __syncthreads(); // all xt reads done; head regions may overwrite xt

    // ---------- scatter q/k (already biased+scaled): packed b64 writes, swizzled ----------
    u16* hb = smem + wave * HEAD_SZ;
    u16* qb = hb;
    u16* kb = hb + K_OFF;
#pragma unroll
    for (int t = 0; t < 4; ++t) {
        u16* base = (t < 2) ? qb : kb;
        int c0 = (16 * (t & 1) + 4 * g) ^ qs;
#pragma unroll
        for (int tt = 0; tt < 4; ++tt) {
            uint2 w2;
            w2.x = pk2(acc_qk[t][tt][0], acc_qk[t][tt][1]);
            w2.y = pk2(acc_qk[t][tt][2], acc_qk[t][tt][3]);
            *reinterpret_cast<uint2*>(&base[(tt * 16 + lr) * 32 + c0]) = w2;
        }
    }
    asm volatile("s_waitcnt lgkmcnt(0)" ::: "memory");

    // ---------- phase 3: S^T = K.Q^T; bias(+mask) via C-init from bMv ----------
    // st[mt][nt][r] = S[q=16nt+lr][j=16mt+4g+r] (log2 domain; -1e30 at padding)
    const f32x4* bv4 = reinterpret_cast<const f32x4*>(bMv);
    f32x4 st[4][4];
    {
        s16x8 ak[4], bq[4];
        int rc = (g * 8) ^ qs;
#pragma unroll
        for (int mt = 0; mt < 4; ++mt)
            ak[mt] = *reinterpret_cast<const s16x8*>(&kb[(mt * 16 + lr) * 32 + rc]);
#pragma unroll
        for (int nt = 0; nt < 4; ++nt)
            bq[nt] = *reinterpret_cast<const s16x8*>(&qb[(nt * 16 + lr) * 32 + rc]);
        __builtin_amdgcn_s_setprio(1);
#pragma unroll
        for (int mt = 0; mt < 4; ++mt)
#pragma unroll
            for (int nt = 0; nt < 4; ++nt)
                st[mt][nt] = __builtin_amdgcn_mfma_f32_16x16x32_bf16(
                    ak[mt], bq[nt], bv4[(((wave * 4 + mt) * 4 + nt) * 4 + g) * 16 + lr], 0, 0, 0);
        __builtin_amdgcn_s_setprio(0);
    }
    // softmax without max-subtraction: |st| <~ 15 << 127, exp2 cannot overflow;
    // padded entries are -1e30 -> exp2 = 0 exactly. Normalization deferred to ov.
    float inv[4];
#pragma unroll
    for (int nt = 0; nt < 4; ++nt) {
        float s = 0.f;
#pragma unroll
        for (int mt = 0; mt < 4; ++mt)
#pragma unroll
            for (int r = 0; r < 4; ++r) {
                float e = exp2f(st[mt][nt][r]);
                st[mt][nt][r] = e;
                s += e;
            }
        s += __shfl_xor(s, 16, 64);
        s += __shfl_xor(s, 32, 64);
        inv[nt] = 1.0f / s;
    }
    // write P (unnormalized e) [64 q][64 j] bf16, XOR-swizzled, over q+k region
    char* pB = reinterpret_cast<char*>(hb);
#pragma unroll
    for (int mt = 0; mt < 4; ++mt)
#pragma unroll
        for (int nt = 0; nt < 4; ++nt) {
            uint2 w2;
            w2.x = pk2(st[mt][nt][0], st[mt][nt][1]);
            w2.y = pk2(st[mt][nt][2], st[mt][nt][3]);
            int q = nt * 16 + lr;
            int off = (q * 128 + mt * 32 + g * 8) ^ ((q & 7) << 4);
            *reinterpret_cast<uint2*>(pB + off) = w2;
        }
    asm volatile("s_waitcnt lgkmcnt(0)" ::: "memory");

    // ---------- phase 4: transposed PV: out^T = V^T . P^T ----------
    const int srcA4 = (((lane & 16) << 1) | lr) << 2; // lane 32*(g&1)+lr, byte index
    const int srcB4 = srcA4 + 64;
    const bool hi32 = (lane & 32) != 0;
    f32x4 ov[2][4] = {};
    {
        s16x8 va[2][2], pbf[4][2];
#pragma unroll
        for (int t1 = 0; t1 < 2; ++t1)
#pragma unroll
            for (int kk = 0; kk < 2; ++kk) {
                union { s16x8 v; unsigned u[4]; } tmp;
#pragma unroll
                for (int w = 0; w < 4; ++w) {
                    int src = (w < 2) ? srcA4 : srcB4;
                    unsigned lo = (unsigned)__builtin_amdgcn_ds_bpermute(src, (int)vpk[2 * kk][t1][w & 1]);
                    unsigned hh = (unsigned)__builtin_amdgcn_ds_bpermute(src, (int)vpk[2 * kk + 1][t1][w & 1]);
                    tmp.u[w] = hi32 ? hh : lo;
                }
                va[t1][kk] = tmp.v;
            }
#pragma unroll
        for (int nt = 0; nt < 4; ++nt)
#pragma unroll
            for (int kk = 0; kk < 2; ++kk) {
                int off = (((nt * 16 + lr) * 128) + kk * 64 + g * 16) ^ ((lr & 7) << 4);
                pbf[nt][kk] = *reinterpret_cast<const s16x8*>(pB + off);
            }
        __builtin_amdgcn_s_setprio(1);
#pragma unroll
        for (int t1 = 0; t1 < 2; ++t1)
#pragma unroll
            for (int nt = 0; nt < 4; ++nt)
#pragma unroll
                for (int kk = 0; kk < 2; ++kk)
                    ov[t1][nt] = __builtin_amdgcn_mfma_f32_16x16x32_bf16(va[t1][kk], pbf[nt][kk], ov[t1][nt], 0, 0, 0);
        __builtin_amdgcn_s_setprio(0);
    }
    // deferred normalization (per q-row scalar)
#pragma unroll
    for (int t1 = 0; t1 < 2; ++t1)
#pragma unroll
        for (int nt = 0; nt < 4; ++nt)
#pragma unroll
            for (int r = 0; r < 4; ++r) ov[t1][nt][r] *= inv[nt];

    // proj A-fragments (global)
    s16x8 pfr[4][2];
    const s16x8* pkpv = reinterpret_cast<const s16x8*>(pkp);
#pragma unroll
    for (int kt = 0; kt < 4; ++kt)
#pragma unroll
        for (int t = 0; t < 2; ++t)
            pfr[kt][t] = pkpv[(kt * 8 + 2 * wave + t) * 64 + lane];

    // ---------- ao chunk into OWN region (no barrier needed before write) ----------
#pragma unroll
    for (int t1 = 0; t1 < 2; ++t1)
#pragma unroll
        for (int nt = 0; nt < 4; ++nt) {
            uint2 w2;
            w2.x = pk2(ov[t1][nt][0], ov[t1][nt][1]);
            w2.y = pk2(ov[t1][nt][2], ov[t1][nt][3]);
            int lg = 2 * t1 + (g >> 1);
            int off = (nt * 16 + lr) * 32 + (((lg << 3) ^ qs)) + ((g & 1) << 2);
            *reinterpret_cast<uint2*>(&hb[off]) = w2;
        }
    __syncthreads(); // single barrier: all ao chunks visible

    // ---------- phase 5: proj^T GEMM (weights as A, ao as B); bias via C-init ----------
    // pacc[t][tt][r] = out[tok=16tt+lr][oc=(2w+t)*16+4g+r]
    f32x4 pacc[2][4];
#pragma unroll
    for (int t = 0; t < 2; ++t) {
        f32x4 pb4 = *reinterpret_cast<const f32x4*>(proj_b + (2 * wave + t) * 16 + 4 * g);
#pragma unroll
        for (int tt = 0; tt < 4; ++tt) pacc[t][tt] = pb4;
    }
#pragma unroll
    for (int kt = 0; kt < 4; ++kt) {
        s16x8 af2[4];
#pragma unroll
        for (int tt = 0; tt < 4; ++tt)
            af2[tt] = *reinterpret_cast<const s16x8*>(&smem[kt * HEAD_SZ + (tt * 16 + lr) * 32 + ((g * 8) ^ qs)]);
        __builtin_amdgcn_s_setprio(1);
#pragma unroll
        for (int t = 0; t < 2; ++t)
#pragma unroll
            for (int tt = 0; tt < 4; ++tt)
                pacc[t][tt] = __builtin_amdgcn_mfma_f32_16x16x32_bf16(pfr[kt][t], af2[tt], pacc[t][tt], 0, 0, 0);
        __builtin_amdgcn_s_setprio(0);
    }
    // stores: tt outer / t inner so the two 64B halves of each 128B line are adjacent
    float* outp = out + (size_t)b * (NTOK * CDIM);
#pragma unroll
    for (int tt = 0; tt < 4; ++tt) {
        int tok = tt * 16 + lr;
        if (tok < NTOK) {
#pragma unroll
            for (int t = 0; t < 2; ++t) {
                int oc0 = (2 * wave + t) * 16 + 4 * g;
                *reinterpret_cast<f32x4*>(outp + (size_t)tok * CDIM + oc0) = pacc[t][tt];
            }
        }
    }
}

extern "C" void kernel_launch(void* const* d_in, const int* in_sizes, int n_in,
                              void* d_out, int out_size, void* d_ws, size_t ws_size,
                              hipStream_t stream) {
    const float* x      = (const float*)d_in[0];
    const float* qkv_w  = (const float*)d_in[1];
    const float* qkv_b  = (const float*)d_in[2];
    const float* proj_w = (const float*)d_in[3];
    const float* proj_b = (const float*)d_in[4];
    const float* rpb    = (const float*)d_in[5];
    const int*   rpi    = (const int*)d_in[6];
    float* out = (float*)d_out;

    u16*   pkq   = (u16*)d_ws;                        // 49152 bf16 (98304 B)
    u16*   pkp   = pkq + 49152;                       // 16384 bf16 (32768 B)
    float* bMv   = (float*)((char*)d_ws + 131072);    // 16384 fp32 (65536 B)
    float* bias2 = (float*)((char*)d_ws + 196608);    // 384 fp32 (1536 B)

    prep_kernel<<<322, 256, 0, stream>>>(qkv_w, proj_w, rpb, rpi, qkv_b, pkq, pkp, bMv, bias2);
    winattn_kernel<<<NWIN, 256, 0, stream>>>(x, bias2, proj_b, pkq, pkp, bMv, out);
}